// Round 1
// baseline (13163.829 us; speedup 1.0000x reference)
//
#include <hip/hip_runtime.h>

// ---------------------------------------------------------------------------
// RGAT-like layer on MI355X.
// Pipeline:
//   K1: feat_src[100000][512](bf16) = node_emb[src_ids] @ w2s + b  (fp32 GEMM)
//   K1: feat_dst[ 50000][512](bf16) = node_emb[src_ids[:50k]] @ w2d + b
//   K2: per-edge logits -> ex=exp(logit) into att slot, atomic denom per (dst,h)
//   K3: att <- ex/(denom+1e-16)   (this IS the "attentions" output)
//   K4: per-edge msg = softmax_D(en*rr*a); g[dst][d] += sum_h msg  (atomics)
//   K5: x_out = leaky0.01((h_dst+g)@w1+b1) -> x_out and emb_cat slots
// Softmax max-subtraction dropped in both places (mathematically identical;
// logits are O(0.1) so exp is numerically safe).
// ---------------------------------------------------------------------------

#define NN_NODES 100000
#define NN_DST   50000

__device__ __forceinline__ float bflo(unsigned u){ return __uint_as_float(u << 16); }
__device__ __forceinline__ float bfhi(unsigned u){ return __uint_as_float(u & 0xFFFF0000u); }
__device__ __forceinline__ unsigned short f2bf(float f){
    unsigned u = __float_as_uint(f);
    unsigned r = (u + 0x7FFFu + ((u >> 16) & 1u)) >> 16;
    return (unsigned short)r;
}

// C_bf16[M][512] = gather(node_emb, ids)[M][128] @ W[128][512] + bias
// block 256, tile 64 rows x 128 cols, grid (ceil(M/64), 4)
__global__ __launch_bounds__(256)
void feat_gemm(const float* __restrict__ node_emb,
               const int* __restrict__ ids,
               const float* __restrict__ W,
               const float* __restrict__ bias,
               unsigned short* __restrict__ out,
               int M)
{
    __shared__ float Alds[64][132];   // [m][k], pad 4 keeps float4 alignment
    const int t = threadIdx.x;
    const int row0 = blockIdx.x * 64;
    const int colbase0 = blockIdx.y * 128;

    #pragma unroll
    for (int i = 0; i < 8; i++){
        int j = t + i * 256;          // 0..2047
        int r = j >> 5;
        int c4 = j & 31;
        int row = row0 + r;
        if (row > M - 1) row = M - 1;
        int nid = ids[row];
        float4 v = ((const float4*)(node_emb + (size_t)nid * 128))[c4];
        *(float4*)&Alds[r][c4 * 4] = v;
    }
    __syncthreads();

    const int tr = t >> 4;            // 0..15 -> rows tr*4..+3
    const int tc = t & 15;            // 0..15 -> cols tc*8..+7
    const int colbase = colbase0 + tc * 8;
    float acc[4][8];
    #pragma unroll
    for (int i = 0; i < 4; i++)
        #pragma unroll
        for (int j = 0; j < 8; j++) acc[i][j] = 0.f;

    const float* Wp = W + colbase;
    #pragma unroll 4
    for (int k = 0; k < 128; k += 4){
        float4 a0 = *(const float4*)&Alds[tr*4+0][k];
        float4 a1 = *(const float4*)&Alds[tr*4+1][k];
        float4 a2 = *(const float4*)&Alds[tr*4+2][k];
        float4 a3 = *(const float4*)&Alds[tr*4+3][k];
        #pragma unroll
        for (int kk = 0; kk < 4; kk++){
            float4 b0 = *(const float4*)(Wp + (k + kk) * 512);
            float4 b1 = *(const float4*)(Wp + (k + kk) * 512 + 4);
            float bb[8] = {b0.x,b0.y,b0.z,b0.w,b1.x,b1.y,b1.z,b1.w};
            float av[4] = { ((const float*)&a0)[kk], ((const float*)&a1)[kk],
                            ((const float*)&a2)[kk], ((const float*)&a3)[kk] };
            #pragma unroll
            for (int i = 0; i < 4; i++)
                #pragma unroll
                for (int j = 0; j < 8; j++)
                    acc[i][j] = fmaf(av[i], bb[j], acc[i][j]);
        }
    }

    float bs[8];
    #pragma unroll
    for (int j = 0; j < 8; j++) bs[j] = bias[colbase + j];
    #pragma unroll
    for (int i = 0; i < 4; i++){
        int row = row0 + tr * 4 + i;
        if (row < M){
            unsigned pw[4];
            #pragma unroll
            for (int jj = 0; jj < 4; jj++){
                unsigned u0 = f2bf(acc[i][2*jj]   + bs[2*jj]);
                unsigned u1 = f2bf(acc[i][2*jj+1] + bs[2*jj+1]);
                pw[jj] = u0 | (u1 << 16);
            }
            uint4 ov = make_uint4(pw[0], pw[1], pw[2], pw[3]);
            *(uint4*)(out + (size_t)row * 512 + colbase) = ov;
        }
    }
}

// one wave per edge; lane -> (h = lane>>4, d0 = (lane&15)*8)
__global__ __launch_bounds__(256)
void edge_logits(const unsigned short* __restrict__ fs,
                 const unsigned short* __restrict__ fd,
                 const int* __restrict__ esrc,
                 const int* __restrict__ edst,
                 const float* __restrict__ attn,
                 float* __restrict__ att_out,
                 float* __restrict__ denom,
                 int E)
{
    const int lane = threadIdx.x & 63;
    const int h = lane >> 4;
    const int g16 = lane & 15;
    const int d0 = g16 * 8;
    float ar[8];
    #pragma unroll
    for (int j = 0; j < 8; j++) ar[j] = attn[h * 128 + d0 + j];

    const int wave = (int)((blockIdx.x * blockDim.x + threadIdx.x) >> 6);
    const int nwaves = (int)((gridDim.x * blockDim.x) >> 6);
    for (int e = wave; e < E; e += nwaves){
        int s  = esrc[e];
        int dt = edst[e];
        const uint4 eu = *(const uint4*)(fs + (size_t)s  * 512 + h * 128 + d0);
        const uint4 du = *(const uint4*)(fd + (size_t)dt * 512 + h * 128 + d0);
        unsigned ue[4] = {eu.x, eu.y, eu.z, eu.w};
        unsigned ud[4] = {du.x, du.y, du.z, du.w};
        float p = 0.f;
        #pragma unroll
        for (int q = 0; q < 4; q++){
            float e0 = bflo(ue[q]) + bflo(ud[q]);
            float e1 = bfhi(ue[q]) + bfhi(ud[q]);
            e0 = fmaxf(e0, 0.2f * e0);     // leaky_relu slope 0.2
            e1 = fmaxf(e1, 0.2f * e1);
            p = fmaf(e0, ar[2*q],   p);
            p = fmaf(e1, ar[2*q+1], p);
        }
        p += __shfl_xor(p, 1);
        p += __shfl_xor(p, 2);
        p += __shfl_xor(p, 4);
        p += __shfl_xor(p, 8);
        if (g16 == 0){
            float ex = __expf(p);          // no max-sub needed: |p| small
            att_out[(size_t)e * 4 + h] = ex;
            atomicAdd(&denom[(size_t)dt * 4 + h], ex);
        }
    }
}

// att[idx] <- att[idx] / (denom[dst*4 + h] + 1e-16)
__global__ __launch_bounds__(256)
void att_norm(float* __restrict__ att,
              const float* __restrict__ denom,
              const int* __restrict__ edst,
              int EH)
{
    int idx = blockIdx.x * 256 + threadIdx.x;
    if (idx < EH){
        int e = idx >> 2;
        int h = idx & 3;
        int dt = edst[e];
        att[idx] = att[idx] / (denom[(size_t)dt * 4 + h] + 1e-16f);
    }
}

__global__ __launch_bounds__(256)
void edge_msg(const unsigned short* __restrict__ fs,
              const float* __restrict__ rel,
              const int* __restrict__ esrc,
              const int* __restrict__ edst,
              const int* __restrict__ ert,
              const float* __restrict__ att,   // already normalized a
              float* __restrict__ gout,
              int E)
{
    const int lane = threadIdx.x & 63;
    const int h = lane >> 4;
    const int g16 = lane & 15;
    const int d0 = g16 * 8;
    const int wave = (int)((blockIdx.x * blockDim.x + threadIdx.x) >> 6);
    const int nwaves = (int)((gridDim.x * blockDim.x) >> 6);
    for (int e = wave; e < E; e += nwaves){
        int s  = esrc[e];
        int dt = edst[e];
        int rt = ert[e];
        const uint4 eu  = *(const uint4*)(fs + (size_t)s * 512 + h * 128 + d0);
        const float4 r0 = *(const float4*)(rel + rt * 128 + d0);
        const float4 r1 = *(const float4*)(rel + rt * 128 + d0 + 4);
        float a = att[(size_t)e * 4 + h];
        unsigned ue[4] = {eu.x, eu.y, eu.z, eu.w};
        float rr[8] = {r0.x,r0.y,r0.z,r0.w,r1.x,r1.y,r1.z,r1.w};
        float ev[8];
        float ssum = 0.f;
        #pragma unroll
        for (int q = 0; q < 4; q++){
            float v0 = bflo(ue[q]) * rr[2*q]   * a;
            float v1 = bfhi(ue[q]) * rr[2*q+1] * a;
            ev[2*q]   = __expf(v0);
            ev[2*q+1] = __expf(v1);
            ssum += ev[2*q] + ev[2*q+1];
        }
        ssum += __shfl_xor(ssum, 1);
        ssum += __shfl_xor(ssum, 2);
        ssum += __shfl_xor(ssum, 4);
        ssum += __shfl_xor(ssum, 8);
        float inv = 1.0f / ssum;               // softmax over D within head
        float m[8];
        #pragma unroll
        for (int j = 0; j < 8; j++){
            m[j] = ev[j] * inv;
            m[j] += __shfl_xor(m[j], 16);      // h0+h1, h2+h3
            m[j] += __shfl_xor(m[j], 32);      // all heads
        }
        if (lane < 16){
            #pragma unroll
            for (int j = 0; j < 8; j++)
                atomicAdd(&gout[(size_t)dt * 128 + d0 + j], m[j]);
        }
    }
}

// x_out = leaky0.01((h_dst+g) @ W1 + b1); write to xout and embcat
__global__ __launch_bounds__(256)
void final_gemm(const float* __restrict__ node_emb,
                const int* __restrict__ ids,
                const float* __restrict__ gbuf,
                const float* __restrict__ W1,
                const float* __restrict__ b1,
                float* __restrict__ xout,
                float* __restrict__ embcat,
                int M)
{
    __shared__ float Alds[64][132];
    const int t = threadIdx.x;
    const int row0 = blockIdx.x * 64;

    #pragma unroll
    for (int i = 0; i < 8; i++){
        int j = t + i * 256;
        int r = j >> 5;
        int c4 = j & 31;
        int row = row0 + r;
        if (row > M - 1) row = M - 1;
        int nid = ids[row];
        float4 v  = ((const float4*)(node_emb + (size_t)nid * 128))[c4];
        float4 gv = ((const float4*)(gbuf + (size_t)row * 128))[c4];
        v.x += gv.x; v.y += gv.y; v.z += gv.z; v.w += gv.w;
        *(float4*)&Alds[r][c4 * 4] = v;
    }
    __syncthreads();

    const int tr = t >> 4;
    const int tc = t & 15;
    const int colbase = tc * 8;
    float acc[4][8];
    #pragma unroll
    for (int i = 0; i < 4; i++)
        #pragma unroll
        for (int j = 0; j < 8; j++) acc[i][j] = 0.f;

    const float* Wp = W1 + colbase;
    #pragma unroll 4
    for (int k = 0; k < 128; k += 4){
        float4 a0 = *(const float4*)&Alds[tr*4+0][k];
        float4 a1 = *(const float4*)&Alds[tr*4+1][k];
        float4 a2 = *(const float4*)&Alds[tr*4+2][k];
        float4 a3 = *(const float4*)&Alds[tr*4+3][k];
        #pragma unroll
        for (int kk = 0; kk < 4; kk++){
            float4 b0 = *(const float4*)(Wp + (k + kk) * 128);
            float4 b1v = *(const float4*)(Wp + (k + kk) * 128 + 4);
            float bb[8] = {b0.x,b0.y,b0.z,b0.w,b1v.x,b1v.y,b1v.z,b1v.w};
            float av[4] = { ((const float*)&a0)[kk], ((const float*)&a1)[kk],
                            ((const float*)&a2)[kk], ((const float*)&a3)[kk] };
            #pragma unroll
            for (int i = 0; i < 4; i++)
                #pragma unroll
                for (int j = 0; j < 8; j++)
                    acc[i][j] = fmaf(av[i], bb[j], acc[i][j]);
        }
    }

    float bs[8];
    #pragma unroll
    for (int j = 0; j < 8; j++) bs[j] = b1[colbase + j];
    #pragma unroll
    for (int i = 0; i < 4; i++){
        int row = row0 + tr * 4 + i;
        if (row < M){
            float o[8];
            #pragma unroll
            for (int j = 0; j < 8; j++){
                float y = acc[i][j] + bs[j];
                o[j] = fmaxf(y, 0.01f * y);    // final leaky slope 0.01
            }
            float4 o0 = make_float4(o[0], o[1], o[2], o[3]);
            float4 o1 = make_float4(o[4], o[5], o[6], o[7]);
            *(float4*)(xout   + (size_t)row * 128 + colbase)     = o0;
            *(float4*)(xout   + (size_t)row * 128 + colbase + 4) = o1;
            *(float4*)(embcat + (size_t)row * 128 + colbase)     = o0;
            *(float4*)(embcat + (size_t)row * 128 + colbase + 4) = o1;
        }
    }
}

extern "C" void kernel_launch(void* const* d_in, const int* in_sizes, int n_in,
                              void* d_out, int out_size, void* d_ws, size_t ws_size,
                              hipStream_t stream)
{
    const int*   src_ids    = (const int*)d_in[0];
    const int*   edge_src   = (const int*)d_in[1];
    const int*   edge_dst   = (const int*)d_in[2];
    const int*   edge_rtype = (const int*)d_in[3];
    const float* node_emb   = (const float*)d_in[4];
    const float* rel_emb    = (const float*)d_in[5];
    const float* w1_w       = (const float*)d_in[6];
    const float* w1_b       = (const float*)d_in[7];
    const float* w2s_w      = (const float*)d_in[8];
    const float* w2s_b      = (const float*)d_in[9];
    const float* w2d_w      = (const float*)d_in[10];
    const float* w2d_b      = (const float*)d_in[11];
    const float* attn       = (const float*)d_in[12];
    const int E = in_sizes[1];             // 3,200,000

    float* out      = (float*)d_out;
    float* x_out    = out;                          // 6.4M
    float* emb_cat  = out + (size_t)6400000;        // 6.4M
    float* g_out    = out + (size_t)12800000;       // 6.4M
    float* att_out  = out + (size_t)19200000;       // 12.8M (E*H)

    char* ws = (char*)d_ws;
    unsigned short* feat_src = (unsigned short*)ws;                      // 102,400,000 B
    unsigned short* feat_dst = (unsigned short*)(ws + 102400000);        //  51,200,000 B
    float*          denom    = (float*)(ws + 153600000);                 //     800,000 B

    hipMemsetAsync(g_out, 0, (size_t)6400000 * 4, stream);
    hipMemsetAsync(denom, 0, (size_t)NN_DST * 4 * 4, stream);

    dim3 b256(256);
    feat_gemm<<<dim3((NN_NODES + 63) / 64, 4), b256, 0, stream>>>(
        node_emb, src_ids, w2s_w, w2s_b, feat_src, NN_NODES);
    feat_gemm<<<dim3((NN_DST + 63) / 64, 4), b256, 0, stream>>>(
        node_emb, src_ids, w2d_w, w2d_b, feat_dst, NN_DST);
    edge_logits<<<8192, b256, 0, stream>>>(
        feat_src, feat_dst, edge_src, edge_dst, attn, att_out, denom, E);
    att_norm<<<(E * 4 + 255) / 256, b256, 0, stream>>>(att_out, denom, edge_dst, E * 4);
    edge_msg<<<8192, b256, 0, stream>>>(
        feat_src, rel_emb, edge_src, edge_dst, edge_rtype, att_out, g_out, E);
    final_gemm<<<(NN_DST + 63) / 64, b256, 0, stream>>>(
        node_emb, src_ids, g_out, w1_w, w1_b, x_out, emb_cat, NN_DST);
}

// Round 2
// 2888.792 us; speedup vs baseline: 4.5569x; 4.5569x over previous
//
#include <hip/hip_runtime.h>

// ---------------------------------------------------------------------------
// RGAT-like layer on MI355X — round 2: atomic-free edge stage.
// Pipeline:
//   K1a/K1b: feat_src/feat_dst (bf16) = gather(node_emb) @ w2{s,d} + b
//   K2: histogram of edge_dst (50k bins, int atomics)
//   K3: exclusive scan (1 block of 1024) -> start[], cursor[]
//   K4: scatter -> sorted edge ids grouped by dst
//   K5: fused per-dst wave: pass1 local attn denominator; pass2 recompute
//       logit, write normalized a, softmax_D message, register-accumulate g,
//       plain stores (no atomics, no memsets for g/denom)
//   K6: x_out = leaky0.01((h_dst+g)@w1+b1) -> x_out and emb_cat
// Max-subtraction in both softmaxes dropped (cancels exactly; logits O(0.1)).
// ---------------------------------------------------------------------------

#define NN_NODES 100000
#define NN_DST   50000
#define NBINS    50000

__device__ __forceinline__ float bflo(unsigned u){ return __uint_as_float(u << 16); }
__device__ __forceinline__ float bfhi(unsigned u){ return __uint_as_float(u & 0xFFFF0000u); }
__device__ __forceinline__ unsigned short f2bf(float f){
    unsigned u = __float_as_uint(f);
    unsigned r = (u + 0x7FFFu + ((u >> 16) & 1u)) >> 16;
    return (unsigned short)r;
}

// C_bf16[M][512] = gather(node_emb, ids)[M][128] @ W[128][512] + bias
__global__ __launch_bounds__(256)
void feat_gemm(const float* __restrict__ node_emb,
               const int* __restrict__ ids,
               const float* __restrict__ W,
               const float* __restrict__ bias,
               unsigned short* __restrict__ out,
               int M)
{
    __shared__ float Alds[64][132];
    const int t = threadIdx.x;
    const int row0 = blockIdx.x * 64;
    const int colbase0 = blockIdx.y * 128;

    #pragma unroll
    for (int i = 0; i < 8; i++){
        int j = t + i * 256;
        int r = j >> 5;
        int c4 = j & 31;
        int row = row0 + r;
        if (row > M - 1) row = M - 1;
        int nid = ids[row];
        float4 v = ((const float4*)(node_emb + (size_t)nid * 128))[c4];
        *(float4*)&Alds[r][c4 * 4] = v;
    }
    __syncthreads();

    const int tr = t >> 4;
    const int tc = t & 15;
    const int colbase = colbase0 + tc * 8;
    float acc[4][8];
    #pragma unroll
    for (int i = 0; i < 4; i++)
        #pragma unroll
        for (int j = 0; j < 8; j++) acc[i][j] = 0.f;

    const float* Wp = W + colbase;
    #pragma unroll 4
    for (int k = 0; k < 128; k += 4){
        float4 a0 = *(const float4*)&Alds[tr*4+0][k];
        float4 a1 = *(const float4*)&Alds[tr*4+1][k];
        float4 a2 = *(const float4*)&Alds[tr*4+2][k];
        float4 a3 = *(const float4*)&Alds[tr*4+3][k];
        #pragma unroll
        for (int kk = 0; kk < 4; kk++){
            float4 b0 = *(const float4*)(Wp + (k + kk) * 512);
            float4 b1 = *(const float4*)(Wp + (k + kk) * 512 + 4);
            float bb[8] = {b0.x,b0.y,b0.z,b0.w,b1.x,b1.y,b1.z,b1.w};
            float av[4] = { ((const float*)&a0)[kk], ((const float*)&a1)[kk],
                            ((const float*)&a2)[kk], ((const float*)&a3)[kk] };
            #pragma unroll
            for (int i = 0; i < 4; i++)
                #pragma unroll
                for (int j = 0; j < 8; j++)
                    acc[i][j] = fmaf(av[i], bb[j], acc[i][j]);
        }
    }

    float bs[8];
    #pragma unroll
    for (int j = 0; j < 8; j++) bs[j] = bias[colbase + j];
    #pragma unroll
    for (int i = 0; i < 4; i++){
        int row = row0 + tr * 4 + i;
        if (row < M){
            unsigned pw[4];
            #pragma unroll
            for (int jj = 0; jj < 4; jj++){
                unsigned u0 = f2bf(acc[i][2*jj]   + bs[2*jj]);
                unsigned u1 = f2bf(acc[i][2*jj+1] + bs[2*jj+1]);
                pw[jj] = u0 | (u1 << 16);
            }
            uint4 ov = make_uint4(pw[0], pw[1], pw[2], pw[3]);
            *(uint4*)(out + (size_t)row * 512 + colbase) = ov;
        }
    }
}

__global__ __launch_bounds__(256)
void hist_kernel(const int* __restrict__ edst, int* __restrict__ cnt, int E)
{
    int idx = blockIdx.x * 256 + threadIdx.x;
    if (idx < E) atomicAdd(&cnt[edst[idx]], 1);
}

// single block, 1024 threads: exclusive scan of cnt[NBINS] -> start/cursor
__global__ __launch_bounds__(1024)
void scan_kernel(const int* __restrict__ cnt,
                 int* __restrict__ start,
                 int* __restrict__ cursor)
{
    __shared__ int sums[1024];
    const int t = threadIdx.x;
    const int CHUNK = (NBINS + 1023) / 1024;     // 49
    int lo = t * CHUNK;
    int hi = lo + CHUNK; if (hi > NBINS) hi = NBINS;
    int s = 0;
    for (int i = lo; i < hi; i++) s += cnt[i];
    sums[t] = s;
    __syncthreads();
    for (int off = 1; off < 1024; off <<= 1){
        int v = sums[t];
        int add = (t >= off) ? sums[t - off] : 0;
        __syncthreads();
        sums[t] = v + add;
        __syncthreads();
    }
    int run = (t == 0) ? 0 : sums[t - 1];
    for (int i = lo; i < hi; i++){
        start[i] = run;
        cursor[i] = run;
        run += cnt[i];
    }
    if (t == 1023) start[NBINS] = sums[1023];
}

__global__ __launch_bounds__(256)
void scatter_kernel(const int* __restrict__ edst,
                    int* __restrict__ cursor,
                    int* __restrict__ sorted,
                    int E)
{
    int idx = blockIdx.x * 256 + threadIdx.x;
    if (idx < E){
        int pos = atomicAdd(&cursor[edst[idx]], 1);
        sorted[pos] = idx;
    }
}

// one wave per dst: logits -> local denom -> normalized a -> softmax_D msg ->
// register g accumulation -> plain stores. lane: h = lane>>4, d0 = (lane&15)*8
__global__ __launch_bounds__(256)
void fused_edge(const unsigned short* __restrict__ fs,
                const unsigned short* __restrict__ fd,
                const float* __restrict__ rel,
                const int* __restrict__ esrc,
                const int* __restrict__ ert,
                const int* __restrict__ sorted,
                const int* __restrict__ start,
                const float* __restrict__ attn,
                float* __restrict__ att_out,
                float* __restrict__ gout)
{
    const int lane = threadIdx.x & 63;
    const int h = lane >> 4;
    const int g16 = lane & 15;
    const int d0 = g16 * 8;
    const int dt = blockIdx.x * 4 + (threadIdx.x >> 6);
    if (dt >= NN_DST) return;

    float ar[8];
    #pragma unroll
    for (int j = 0; j < 8; j++) ar[j] = attn[h * 128 + d0 + j];

    // feat_dst fragment for this dst, loaded once
    const uint4 du = *(const uint4*)(fd + (size_t)dt * 512 + h * 128 + d0);
    const unsigned udv[4] = {du.x, du.y, du.z, du.w};
    float fdv[8];
    #pragma unroll
    for (int q = 0; q < 4; q++){ fdv[2*q] = bflo(udv[q]); fdv[2*q+1] = bfhi(udv[q]); }

    const int beg = start[dt];
    const int end = start[dt + 1];

    // ---- pass 1: attention softmax denominator (per head, in registers) ----
    float den = 0.f;
    for (int i = beg; i < end; i++){
        int e = sorted[i];
        int s = esrc[e];
        const uint4 eu = *(const uint4*)(fs + (size_t)s * 512 + h * 128 + d0);
        const unsigned ue[4] = {eu.x, eu.y, eu.z, eu.w};
        float p = 0.f;
        #pragma unroll
        for (int q = 0; q < 4; q++){
            float e0 = bflo(ue[q]) + fdv[2*q];
            float e1 = bfhi(ue[q]) + fdv[2*q+1];
            e0 = fmaxf(e0, 0.2f * e0);
            e1 = fmaxf(e1, 0.2f * e1);
            p = fmaf(e0, ar[2*q],   p);
            p = fmaf(e1, ar[2*q+1], p);
        }
        p += __shfl_xor(p, 1);
        p += __shfl_xor(p, 2);
        p += __shfl_xor(p, 4);
        p += __shfl_xor(p, 8);
        den += __expf(p);          // identical across the 16-lane head group
    }
    const float invden = 1.0f / (den + 1e-16f);

    // ---- pass 2: recompute logit, write a, message softmax, accumulate g ---
    float acc[8];
    #pragma unroll
    for (int j = 0; j < 8; j++) acc[j] = 0.f;

    for (int i = beg; i < end; i++){
        int e  = sorted[i];
        int s  = esrc[e];
        int rt = ert[e];
        const uint4 eu  = *(const uint4*)(fs + (size_t)s * 512 + h * 128 + d0);
        const float4 r0 = *(const float4*)(rel + rt * 128 + d0);
        const float4 r1 = *(const float4*)(rel + rt * 128 + d0 + 4);
        const unsigned ue[4] = {eu.x, eu.y, eu.z, eu.w};
        float p = 0.f;
        #pragma unroll
        for (int q = 0; q < 4; q++){
            float e0 = bflo(ue[q]) + fdv[2*q];
            float e1 = bfhi(ue[q]) + fdv[2*q+1];
            e0 = fmaxf(e0, 0.2f * e0);
            e1 = fmaxf(e1, 0.2f * e1);
            p = fmaf(e0, ar[2*q],   p);
            p = fmaf(e1, ar[2*q+1], p);
        }
        p += __shfl_xor(p, 1);
        p += __shfl_xor(p, 2);
        p += __shfl_xor(p, 4);
        p += __shfl_xor(p, 8);
        float a = __expf(p) * invden;
        if (g16 == 0) att_out[(size_t)e * 4 + h] = a;

        float rr[8] = {r0.x,r0.y,r0.z,r0.w,r1.x,r1.y,r1.z,r1.w};
        float ev[8];
        float ssum = 0.f;
        #pragma unroll
        for (int q = 0; q < 4; q++){
            float v0 = bflo(ue[q]) * rr[2*q]   * a;
            float v1 = bfhi(ue[q]) * rr[2*q+1] * a;
            ev[2*q]   = __expf(v0);
            ev[2*q+1] = __expf(v1);
            ssum += ev[2*q] + ev[2*q+1];
        }
        ssum += __shfl_xor(ssum, 1);
        ssum += __shfl_xor(ssum, 2);
        ssum += __shfl_xor(ssum, 4);
        ssum += __shfl_xor(ssum, 8);
        float inv = 1.0f / ssum;
        #pragma unroll
        for (int j = 0; j < 8; j++) acc[j] = fmaf(ev[j], inv, acc[j]);
    }

    // reduce over heads and store (one wave owns this dst: plain stores)
    #pragma unroll
    for (int j = 0; j < 8; j++){
        acc[j] += __shfl_xor(acc[j], 16);
        acc[j] += __shfl_xor(acc[j], 32);
    }
    if (lane < 16){
        float4 o0 = make_float4(acc[0], acc[1], acc[2], acc[3]);
        float4 o1 = make_float4(acc[4], acc[5], acc[6], acc[7]);
        *(float4*)(gout + (size_t)dt * 128 + d0)     = o0;
        *(float4*)(gout + (size_t)dt * 128 + d0 + 4) = o1;
    }
}

// x_out = leaky0.01((h_dst+g) @ W1 + b1); write to xout and embcat
__global__ __launch_bounds__(256)
void final_gemm(const float* __restrict__ node_emb,
                const int* __restrict__ ids,
                const float* __restrict__ gbuf,
                const float* __restrict__ W1,
                const float* __restrict__ b1,
                float* __restrict__ xout,
                float* __restrict__ embcat,
                int M)
{
    __shared__ float Alds[64][132];
    const int t = threadIdx.x;
    const int row0 = blockIdx.x * 64;

    #pragma unroll
    for (int i = 0; i < 8; i++){
        int j = t + i * 256;
        int r = j >> 5;
        int c4 = j & 31;
        int row = row0 + r;
        if (row > M - 1) row = M - 1;
        int nid = ids[row];
        float4 v  = ((const float4*)(node_emb + (size_t)nid * 128))[c4];
        float4 gv = ((const float4*)(gbuf + (size_t)row * 128))[c4];
        v.x += gv.x; v.y += gv.y; v.z += gv.z; v.w += gv.w;
        *(float4*)&Alds[r][c4 * 4] = v;
    }
    __syncthreads();

    const int tr = t >> 4;
    const int tc = t & 15;
    const int colbase = tc * 8;
    float acc[4][8];
    #pragma unroll
    for (int i = 0; i < 4; i++)
        #pragma unroll
        for (int j = 0; j < 8; j++) acc[i][j] = 0.f;

    const float* Wp = W1 + colbase;
    #pragma unroll 4
    for (int k = 0; k < 128; k += 4){
        float4 a0 = *(const float4*)&Alds[tr*4+0][k];
        float4 a1 = *(const float4*)&Alds[tr*4+1][k];
        float4 a2 = *(const float4*)&Alds[tr*4+2][k];
        float4 a3 = *(const float4*)&Alds[tr*4+3][k];
        #pragma unroll
        for (int kk = 0; kk < 4; kk++){
            float4 b0 = *(const float4*)(Wp + (k + kk) * 128);
            float4 b1v = *(const float4*)(Wp + (k + kk) * 128 + 4);
            float bb[8] = {b0.x,b0.y,b0.z,b0.w,b1v.x,b1v.y,b1v.z,b1v.w};
            float av[4] = { ((const float*)&a0)[kk], ((const float*)&a1)[kk],
                            ((const float*)&a2)[kk], ((const float*)&a3)[kk] };
            #pragma unroll
            for (int i = 0; i < 4; i++)
                #pragma unroll
                for (int j = 0; j < 8; j++)
                    acc[i][j] = fmaf(av[i], bb[j], acc[i][j]);
        }
    }

    float bs[8];
    #pragma unroll
    for (int j = 0; j < 8; j++) bs[j] = b1[colbase + j];
    #pragma unroll
    for (int i = 0; i < 4; i++){
        int row = row0 + tr * 4 + i;
        if (row < M){
            float o[8];
            #pragma unroll
            for (int j = 0; j < 8; j++){
                float y = acc[i][j] + bs[j];
                o[j] = fmaxf(y, 0.01f * y);
            }
            float4 o0 = make_float4(o[0], o[1], o[2], o[3]);
            float4 o1 = make_float4(o[4], o[5], o[6], o[7]);
            *(float4*)(xout   + (size_t)row * 128 + colbase)     = o0;
            *(float4*)(xout   + (size_t)row * 128 + colbase + 4) = o1;
            *(float4*)(embcat + (size_t)row * 128 + colbase)     = o0;
            *(float4*)(embcat + (size_t)row * 128 + colbase + 4) = o1;
        }
    }
}

extern "C" void kernel_launch(void* const* d_in, const int* in_sizes, int n_in,
                              void* d_out, int out_size, void* d_ws, size_t ws_size,
                              hipStream_t stream)
{
    const int*   src_ids    = (const int*)d_in[0];
    const int*   edge_src   = (const int*)d_in[1];
    const int*   edge_dst   = (const int*)d_in[2];
    const int*   edge_rtype = (const int*)d_in[3];
    const float* node_emb   = (const float*)d_in[4];
    const float* rel_emb    = (const float*)d_in[5];
    const float* w1_w       = (const float*)d_in[6];
    const float* w1_b       = (const float*)d_in[7];
    const float* w2s_w      = (const float*)d_in[8];
    const float* w2s_b      = (const float*)d_in[9];
    const float* w2d_w      = (const float*)d_in[10];
    const float* w2d_b      = (const float*)d_in[11];
    const float* attn       = (const float*)d_in[12];
    const int E = in_sizes[1];             // 3,200,000

    float* out      = (float*)d_out;
    float* x_out    = out;                          // 50000*128
    float* emb_cat  = out + (size_t)6400000;        // 50000*128
    float* g_out    = out + (size_t)12800000;       // 50000*128
    float* att_out  = out + (size_t)19200000;       // E*4

    char* ws = (char*)d_ws;
    unsigned short* feat_src = (unsigned short*)ws;                       // 102,400,000 B
    unsigned short* feat_dst = (unsigned short*)(ws + 102400000);         //  51,200,000 B
    int*  cnt    = (int*)(ws + 153600000);                                //     200,000 B
    int*  start  = (int*)(ws + 153800000);                                //     200,004 B
    int*  cursor = (int*)(ws + 154000008);                                //     200,000 B
    int*  sorted = (int*)(ws + 154200008);                                //   E*4 B

    hipMemsetAsync(cnt, 0, NBINS * sizeof(int), stream);

    dim3 b256(256);
    feat_gemm<<<dim3((NN_NODES + 63) / 64, 4), b256, 0, stream>>>(
        node_emb, src_ids, w2s_w, w2s_b, feat_src, NN_NODES);
    feat_gemm<<<dim3((NN_DST + 63) / 64, 4), b256, 0, stream>>>(
        node_emb, src_ids, w2d_w, w2d_b, feat_dst, NN_DST);
    hist_kernel<<<(E + 255) / 256, b256, 0, stream>>>(edge_dst, cnt, E);
    scan_kernel<<<1, 1024, 0, stream>>>(cnt, start, cursor);
    scatter_kernel<<<(E + 255) / 256, b256, 0, stream>>>(edge_dst, cursor, sorted, E);
    fused_edge<<<(NN_DST + 3) / 4, b256, 0, stream>>>(
        feat_src, feat_dst, rel_emb, edge_src, edge_rtype, sorted, start,
        attn, att_out, g_out);
    final_gemm<<<(NN_DST + 63) / 64, b256, 0, stream>>>(
        node_emb, src_ids, g_out, w1_w, w1_b, x_out, emb_cat, NN_DST);
}

// Round 3
// 2091.416 us; speedup vs baseline: 6.2942x; 1.3813x over previous
//
#include <hip/hip_runtime.h>

// ---------------------------------------------------------------------------
// RGAT-like layer on MI355X — round 3.
//   K0 : transpose+bf16-convert W2s/W2d -> Wt[512][128] (aliased in ws)
//   K1 : MFMA feat GEMM: feat = gather(node_emb)@W + b  (bf16 in/out, fp32 acc)
//   K2 : histogram of edge_dst
//   K3 : exclusive scan (1 block)
//   K4 : scatter -> s_ert[i] = (edge_id<<5)|rtype, grouped by dst
//   K5 : fused per-dst wave: pass1 logit->ex (stored raw to att slot) + denom;
//        pass2 read ex back, normalize, softmax_D message, register g, stores.
//   K6 : final SIMT GEMM -> x_out, emb_cat
// ---------------------------------------------------------------------------

#define NN_NODES 100000
#define NN_DST   50000
#define NBINS    50000

typedef short short8 __attribute__((ext_vector_type(8)));
typedef float f32x4  __attribute__((ext_vector_type(4)));

__device__ __forceinline__ float bflo(unsigned u){ return __uint_as_float(u << 16); }
__device__ __forceinline__ float bfhi(unsigned u){ return __uint_as_float(u & 0xFFFF0000u); }
__device__ __forceinline__ unsigned short f2bf(float f){
    unsigned u = __float_as_uint(f);
    unsigned r = (u + 0x7FFFu + ((u >> 16) & 1u)) >> 16;
    return (unsigned short)r;
}

// ---------------- K0: W[128][512] fp32 -> Wt[512][128] bf16 -----------------
__global__ __launch_bounds__(256)
void transpose_w(const float* __restrict__ W, unsigned short* __restrict__ Wt)
{
    int idx = blockIdx.x * 256 + threadIdx.x;   // 65536 total
    int n = idx >> 7, k = idx & 127;
    Wt[idx] = f2bf(W[k * 512 + n]);
}

// ---------------- K1: MFMA feat GEMM ----------------------------------------
// out_bf16[M][512] = gather(node_emb, ids)[M][128] @ W[128][512] + bias
// block 256 (4 waves), tile 64 rows; loops over 8 col-slices of 64.
__device__ __forceinline__ short8 pack_bf8(float4 a, float4 b){
    short8 r;
    r[0] = (short)f2bf(a.x); r[1] = (short)f2bf(a.y);
    r[2] = (short)f2bf(a.z); r[3] = (short)f2bf(a.w);
    r[4] = (short)f2bf(b.x); r[5] = (short)f2bf(b.y);
    r[6] = (short)f2bf(b.z); r[7] = (short)f2bf(b.w);
    return r;
}

__global__ __launch_bounds__(256)
void feat_gemm_mfma(const float* __restrict__ node_emb,
                    const int* __restrict__ ids,
                    const unsigned short* __restrict__ Wt,   // [512][128] bf16
                    const float* __restrict__ bias,
                    unsigned short* __restrict__ out,        // [M][512] bf16
                    int M)
{
    const int t    = threadIdx.x;
    const int lane = t & 63;
    const int w    = t >> 6;
    const int quad = lane >> 4;
    const int l15  = lane & 15;
    const int m0   = blockIdx.x * 64;

    // A fragments: lane supplies A[m=l15][k=quad*8+j] for its wave's 16 rows
    int arowi = m0 + w * 16 + l15;
    if (arowi > M - 1) arowi = M - 1;
    const float* arow = node_emb + (size_t)ids[arowi] * 128;

    short8 afrag[4];
    #pragma unroll
    for (int s = 0; s < 4; s++){
        float4 v0 = *(const float4*)(arow + s * 32 + quad * 8);
        float4 v1 = *(const float4*)(arow + s * 32 + quad * 8 + 4);
        afrag[s] = pack_bf8(v0, v1);
    }

    for (int sl = 0; sl < 8; sl++){
        const int n0 = sl * 64;
        short8 bfrag[4][4];
        #pragma unroll
        for (int s = 0; s < 4; s++)
            #pragma unroll
            for (int c = 0; c < 4; c++)
                bfrag[s][c] = *(const short8*)(Wt + (size_t)(n0 + c * 16 + l15) * 128
                                               + s * 32 + quad * 8);
        f32x4 acc[4];
        #pragma unroll
        for (int c = 0; c < 4; c++) acc[c] = (f32x4){0.f, 0.f, 0.f, 0.f};
        #pragma unroll
        for (int s = 0; s < 4; s++)
            #pragma unroll
            for (int c = 0; c < 4; c++)
                acc[c] = __builtin_amdgcn_mfma_f32_16x16x32_bf16(
                             afrag[s], bfrag[s][c], acc[c], 0, 0, 0);
        // C/D: col = lane&15, row = quad*4 + reg
        #pragma unroll
        for (int c = 0; c < 4; c++){
            int colg = n0 + c * 16 + l15;
            float bv = bias[colg];
            #pragma unroll
            for (int r = 0; r < 4; r++){
                int rowg = m0 + w * 16 + quad * 4 + r;
                if (rowg < M)
                    out[(size_t)rowg * 512 + colg] = f2bf(acc[c][r] + bv);
            }
        }
    }
}

// ---------------- K2/K3/K4: counting sort by dst ----------------------------
__global__ __launch_bounds__(256)
void hist_kernel(const int* __restrict__ edst, int* __restrict__ cnt, int E)
{
    int idx = blockIdx.x * 256 + threadIdx.x;
    if (idx < E) atomicAdd(&cnt[edst[idx]], 1);
}

__global__ __launch_bounds__(1024)
void scan_kernel(const int* __restrict__ cnt,
                 int* __restrict__ start,
                 int* __restrict__ cursor)
{
    __shared__ int sums[1024];
    const int t = threadIdx.x;
    const int CHUNK = (NBINS + 1023) / 1024;
    int lo = t * CHUNK;
    int hi = lo + CHUNK; if (hi > NBINS) hi = NBINS;
    int s = 0;
    for (int i = lo; i < hi; i++) s += cnt[i];
    sums[t] = s;
    __syncthreads();
    for (int off = 1; off < 1024; off <<= 1){
        int v = sums[t];
        int add = (t >= off) ? sums[t - off] : 0;
        __syncthreads();
        sums[t] = v + add;
        __syncthreads();
    }
    int run = (t == 0) ? 0 : sums[t - 1];
    for (int i = lo; i < hi; i++){
        start[i] = run;
        cursor[i] = run;
        run += cnt[i];
    }
    if (t == 1023) start[NBINS] = sums[1023];
}

__global__ __launch_bounds__(256)
void scatter_kernel(const int* __restrict__ edst,
                    const int* __restrict__ ert,
                    int* __restrict__ cursor,
                    int* __restrict__ s_ert,
                    int E)
{
    int idx = blockIdx.x * 256 + threadIdx.x;
    if (idx < E){
        int pos = atomicAdd(&cursor[edst[idx]], 1);
        s_ert[pos] = (idx << 5) | ert[idx];
    }
}

// ---------------- K5: fused per-dst edge stage ------------------------------
__device__ __forceinline__ float logit_part(uint4 u, const float* fdv, const float* ar){
    unsigned uu[4] = {u.x, u.y, u.z, u.w};
    float p = 0.f;
    #pragma unroll
    for (int q = 0; q < 4; q++){
        float e0 = bflo(uu[q]) + fdv[2*q];
        float e1 = bfhi(uu[q]) + fdv[2*q+1];
        e0 = fmaxf(e0, 0.2f * e0);
        e1 = fmaxf(e1, 0.2f * e1);
        p = fmaf(e0, ar[2*q],   p);
        p = fmaf(e1, ar[2*q+1], p);
    }
    return p;
}

__device__ __forceinline__ float msg_ev(uint4 u, const float* rr, float a, float* ev){
    unsigned uu[4] = {u.x, u.y, u.z, u.w};
    float ss = 0.f;
    #pragma unroll
    for (int q = 0; q < 4; q++){
        float v0 = bflo(uu[q]) * rr[2*q]   * a;
        float v1 = bfhi(uu[q]) * rr[2*q+1] * a;
        ev[2*q]   = __expf(v0);
        ev[2*q+1] = __expf(v1);
        ss += ev[2*q] + ev[2*q+1];
    }
    return ss;
}

__global__ __launch_bounds__(256)
void fused_edge(const unsigned short* __restrict__ fs,
                const unsigned short* __restrict__ fd,
                const float* __restrict__ rel,
                const int* __restrict__ esrc,
                const int* __restrict__ s_ert,
                const int* __restrict__ start,
                const float* __restrict__ attn,
                float* __restrict__ att_out,
                float* __restrict__ gout)
{
    const int lane = threadIdx.x & 63;
    const int h = lane >> 4;
    const int g16 = lane & 15;
    const int d0 = g16 * 8;
    const int dt = blockIdx.x * 4 + (threadIdx.x >> 6);
    if (dt >= NN_DST) return;

    float ar[8];
    #pragma unroll
    for (int j = 0; j < 8; j++) ar[j] = attn[h * 128 + d0 + j];

    const uint4 du = *(const uint4*)(fd + (size_t)dt * 512 + h * 128 + d0);
    const unsigned udv[4] = {du.x, du.y, du.z, du.w};
    float fdv[8];
    #pragma unroll
    for (int q = 0; q < 4; q++){ fdv[2*q] = bflo(udv[q]); fdv[2*q+1] = bfhi(udv[q]); }

    const int beg = start[dt];
    const int end = start[dt + 1];

    // ---- pass 1: ex per edge (stored raw by ALL lanes), denominator --------
    float den = 0.f;
    int i = beg;
    for (; i + 2 <= end; i += 2){
        int pk0 = s_ert[i], pk1 = s_ert[i + 1];
        int e0 = pk0 >> 5,  e1 = pk1 >> 5;
        int s0 = esrc[e0],  s1 = esrc[e1];
        uint4 ua = *(const uint4*)(fs + (size_t)s0 * 512 + h * 128 + d0);
        uint4 ub = *(const uint4*)(fs + (size_t)s1 * 512 + h * 128 + d0);
        float pa = logit_part(ua, fdv, ar);
        float pb = logit_part(ub, fdv, ar);
        pa += __shfl_xor(pa, 1);  pb += __shfl_xor(pb, 1);
        pa += __shfl_xor(pa, 2);  pb += __shfl_xor(pb, 2);
        pa += __shfl_xor(pa, 4);  pb += __shfl_xor(pb, 4);
        pa += __shfl_xor(pa, 8);  pb += __shfl_xor(pb, 8);
        float xa = __expf(pa), xb = __expf(pb);
        den += xa + xb;
        // all lanes store (each lane later reads its own write: coherent)
        att_out[(size_t)e0 * 4 + h] = xa;
        att_out[(size_t)e1 * 4 + h] = xb;
    }
    if (i < end){
        int pk0 = s_ert[i];
        int e0 = pk0 >> 5;
        int s0 = esrc[e0];
        uint4 ua = *(const uint4*)(fs + (size_t)s0 * 512 + h * 128 + d0);
        float pa = logit_part(ua, fdv, ar);
        pa += __shfl_xor(pa, 1);
        pa += __shfl_xor(pa, 2);
        pa += __shfl_xor(pa, 4);
        pa += __shfl_xor(pa, 8);
        float xa = __expf(pa);
        den += xa;
        att_out[(size_t)e0 * 4 + h] = xa;
    }
    const float invden = 1.0f / (den + 1e-16f);

    // ---- pass 2: normalize a, message softmax, accumulate g ----------------
    float acc[8];
    #pragma unroll
    for (int j = 0; j < 8; j++) acc[j] = 0.f;

    i = beg;
    for (; i + 2 <= end; i += 2){
        int pk0 = s_ert[i], pk1 = s_ert[i + 1];
        int e0 = pk0 >> 5,  e1 = pk1 >> 5;
        int rt0 = pk0 & 31, rt1 = pk1 & 31;
        int s0 = esrc[e0],  s1 = esrc[e1];
        uint4 ua = *(const uint4*)(fs + (size_t)s0 * 512 + h * 128 + d0);
        uint4 ub = *(const uint4*)(fs + (size_t)s1 * 512 + h * 128 + d0);
        float4 ra0 = *(const float4*)(rel + rt0 * 128 + d0);
        float4 ra1 = *(const float4*)(rel + rt0 * 128 + d0 + 4);
        float4 rb0 = *(const float4*)(rel + rt1 * 128 + d0);
        float4 rb1 = *(const float4*)(rel + rt1 * 128 + d0 + 4);
        float aa = att_out[(size_t)e0 * 4 + h] * invden;
        float ab = att_out[(size_t)e1 * 4 + h] * invden;
        if (g16 == 0){
            att_out[(size_t)e0 * 4 + h] = aa;
            att_out[(size_t)e1 * 4 + h] = ab;
        }
        float rra[8] = {ra0.x, ra0.y, ra0.z, ra0.w, ra1.x, ra1.y, ra1.z, ra1.w};
        float rrb[8] = {rb0.x, rb0.y, rb0.z, rb0.w, rb1.x, rb1.y, rb1.z, rb1.w};
        float eva[8], evb[8];
        float sa = msg_ev(ua, rra, aa, eva);
        float sb = msg_ev(ub, rrb, ab, evb);
        sa += __shfl_xor(sa, 1);  sb += __shfl_xor(sb, 1);
        sa += __shfl_xor(sa, 2);  sb += __shfl_xor(sb, 2);
        sa += __shfl_xor(sa, 4);  sb += __shfl_xor(sb, 4);
        sa += __shfl_xor(sa, 8);  sb += __shfl_xor(sb, 8);
        float ia = 1.0f / sa, ib = 1.0f / sb;
        #pragma unroll
        for (int j = 0; j < 8; j++){
            acc[j] = fmaf(eva[j], ia, acc[j]);
            acc[j] = fmaf(evb[j], ib, acc[j]);
        }
    }
    if (i < end){
        int pk0 = s_ert[i];
        int e0 = pk0 >> 5;
        int rt0 = pk0 & 31;
        int s0 = esrc[e0];
        uint4 ua = *(const uint4*)(fs + (size_t)s0 * 512 + h * 128 + d0);
        float4 ra0 = *(const float4*)(rel + rt0 * 128 + d0);
        float4 ra1 = *(const float4*)(rel + rt0 * 128 + d0 + 4);
        float aa = att_out[(size_t)e0 * 4 + h] * invden;
        if (g16 == 0) att_out[(size_t)e0 * 4 + h] = aa;
        float rra[8] = {ra0.x, ra0.y, ra0.z, ra0.w, ra1.x, ra1.y, ra1.z, ra1.w};
        float eva[8];
        float sa = msg_ev(ua, rra, aa, eva);
        sa += __shfl_xor(sa, 1);
        sa += __shfl_xor(sa, 2);
        sa += __shfl_xor(sa, 4);
        sa += __shfl_xor(sa, 8);
        float ia = 1.0f / sa;
        #pragma unroll
        for (int j = 0; j < 8; j++) acc[j] = fmaf(eva[j], ia, acc[j]);
    }

    #pragma unroll
    for (int j = 0; j < 8; j++){
        acc[j] += __shfl_xor(acc[j], 16);
        acc[j] += __shfl_xor(acc[j], 32);
    }
    if (lane < 16){
        float4 o0 = make_float4(acc[0], acc[1], acc[2], acc[3]);
        float4 o1 = make_float4(acc[4], acc[5], acc[6], acc[7]);
        *(float4*)(gout + (size_t)dt * 128 + d0)     = o0;
        *(float4*)(gout + (size_t)dt * 128 + d0 + 4) = o1;
    }
}

// ---------------- K6: final SIMT GEMM ---------------------------------------
__global__ __launch_bounds__(256)
void final_gemm(const float* __restrict__ node_emb,
                const int* __restrict__ ids,
                const float* __restrict__ gbuf,
                const float* __restrict__ W1,
                const float* __restrict__ b1,
                float* __restrict__ xout,
                float* __restrict__ embcat,
                int M)
{
    __shared__ float Alds[64][132];
    const int t = threadIdx.x;
    const int row0 = blockIdx.x * 64;

    #pragma unroll
    for (int i = 0; i < 8; i++){
        int j = t + i * 256;
        int r = j >> 5;
        int c4 = j & 31;
        int row = row0 + r;
        if (row > M - 1) row = M - 1;
        int nid = ids[row];
        float4 v  = ((const float4*)(node_emb + (size_t)nid * 128))[c4];
        float4 gv = ((const float4*)(gbuf + (size_t)row * 128))[c4];
        v.x += gv.x; v.y += gv.y; v.z += gv.z; v.w += gv.w;
        *(float4*)&Alds[r][c4 * 4] = v;
    }
    __syncthreads();

    const int tr = t >> 4;
    const int tc = t & 15;
    const int colbase = tc * 8;
    float acc[4][8];
    #pragma unroll
    for (int i = 0; i < 4; i++)
        #pragma unroll
        for (int j = 0; j < 8; j++) acc[i][j] = 0.f;

    const float* Wp = W1 + colbase;
    #pragma unroll 4
    for (int k = 0; k < 128; k += 4){
        float4 a0 = *(const float4*)&Alds[tr*4+0][k];
        float4 a1 = *(const float4*)&Alds[tr*4+1][k];
        float4 a2 = *(const float4*)&Alds[tr*4+2][k];
        float4 a3 = *(const float4*)&Alds[tr*4+3][k];
        #pragma unroll
        for (int kk = 0; kk < 4; kk++){
            float4 b0  = *(const float4*)(Wp + (k + kk) * 128);
            float4 b1v = *(const float4*)(Wp + (k + kk) * 128 + 4);
            float bb[8] = {b0.x,b0.y,b0.z,b0.w,b1v.x,b1v.y,b1v.z,b1v.w};
            float av[4] = { ((const float*)&a0)[kk], ((const float*)&a1)[kk],
                            ((const float*)&a2)[kk], ((const float*)&a3)[kk] };
            #pragma unroll
            for (int i = 0; i < 4; i++)
                #pragma unroll
                for (int j = 0; j < 8; j++)
                    acc[i][j] = fmaf(av[i], bb[j], acc[i][j]);
        }
    }

    float bs[8];
    #pragma unroll
    for (int j = 0; j < 8; j++) bs[j] = b1[colbase + j];
    #pragma unroll
    for (int i = 0; i < 4; i++){
        int row = row0 + tr * 4 + i;
        if (row < M){
            float o[8];
            #pragma unroll
            for (int j = 0; j < 8; j++){
                float y = acc[i][j] + bs[j];
                o[j] = fmaxf(y, 0.01f * y);
            }
            float4 o0 = make_float4(o[0], o[1], o[2], o[3]);
            float4 o1 = make_float4(o[4], o[5], o[6], o[7]);
            *(float4*)(xout   + (size_t)row * 128 + colbase)     = o0;
            *(float4*)(xout   + (size_t)row * 128 + colbase + 4) = o1;
            *(float4*)(embcat + (size_t)row * 128 + colbase)     = o0;
            *(float4*)(embcat + (size_t)row * 128 + colbase + 4) = o1;
        }
    }
}

extern "C" void kernel_launch(void* const* d_in, const int* in_sizes, int n_in,
                              void* d_out, int out_size, void* d_ws, size_t ws_size,
                              hipStream_t stream)
{
    const int*   src_ids    = (const int*)d_in[0];
    const int*   edge_src   = (const int*)d_in[1];
    const int*   edge_dst   = (const int*)d_in[2];
    const int*   edge_rtype = (const int*)d_in[3];
    const float* node_emb   = (const float*)d_in[4];
    const float* rel_emb    = (const float*)d_in[5];
    const float* w1_w       = (const float*)d_in[6];
    const float* w1_b       = (const float*)d_in[7];
    const float* w2s_w      = (const float*)d_in[8];
    const float* w2s_b      = (const float*)d_in[9];
    const float* w2d_w      = (const float*)d_in[10];
    const float* w2d_b      = (const float*)d_in[11];
    const float* attn       = (const float*)d_in[12];
    const int E = in_sizes[1];             // 3,200,000

    float* out      = (float*)d_out;
    float* x_out    = out;                          // 50000*128
    float* emb_cat  = out + (size_t)6400000;        // 50000*128
    float* g_out    = out + (size_t)12800000;       // 50000*128
    float* att_out  = out + (size_t)19200000;       // E*4

    char* ws = (char*)d_ws;
    unsigned short* feat_src = (unsigned short*)ws;                       // 102,400,000 B
    unsigned short* feat_dst = (unsigned short*)(ws + 102400000);         //  51,200,000 B
    int*  cnt    = (int*)(ws + 153600000);                                //     200,000 B
    int*  start  = (int*)(ws + 153800000);                                //     200,004 B
    int*  cursor = (int*)(ws + 154000008);                                //     200,000 B
    int*  s_ert  = (int*)(ws + 154200008);                                //   E*4 B
    // Wt buffers alias the s_ert region: used only BEFORE scatter writes it
    unsigned short* w2s_t = (unsigned short*)(ws + 154200008);            //     131,072 B
    unsigned short* w2d_t = (unsigned short*)(ws + 154331080);            //     131,072 B

    hipMemsetAsync(cnt, 0, NBINS * sizeof(int), stream);

    dim3 b256(256);
    transpose_w<<<256, b256, 0, stream>>>(w2s_w, w2s_t);
    transpose_w<<<256, b256, 0, stream>>>(w2d_w, w2d_t);
    feat_gemm_mfma<<<(NN_NODES + 63) / 64, b256, 0, stream>>>(
        node_emb, src_ids, w2s_t, w2s_b, feat_src, NN_NODES);
    feat_gemm_mfma<<<(NN_DST + 63) / 64, b256, 0, stream>>>(
        node_emb, src_ids, w2d_t, w2d_b, feat_dst, NN_DST);
    hist_kernel<<<(E + 255) / 256, b256, 0, stream>>>(edge_dst, cnt, E);
    scan_kernel<<<1, 1024, 0, stream>>>(cnt, start, cursor);
    scatter_kernel<<<(E + 255) / 256, b256, 0, stream>>>(
        edge_dst, edge_rtype, cursor, s_ert, E);
    fused_edge<<<(NN_DST + 3) / 4, b256, 0, stream>>>(
        feat_src, feat_dst, rel_emb, edge_src, s_ert, start,
        attn, att_out, g_out);
    final_gemm<<<(NN_DST + 63) / 64, b256, 0, stream>>>(
        node_emb, src_ids, g_out, w1_w, w1_b, x_out, emb_cat, NN_DST);
}